// Round 3
// baseline (84.636 us; speedup 1.0000x reference)
//
#include <hip/hip_runtime.h>
#include <math.h>

typedef __attribute__((ext_vector_type(8))) short short8;
typedef __attribute__((ext_vector_type(4))) float f32x4;

#define GLOBAL_AS __attribute__((address_space(1)))
#define LDS_AS __attribute__((address_space(3)))

__device__ inline short f2bf(float f) {
    unsigned u = __float_as_uint(f);
    u += 0x7FFFu + ((u >> 16) & 1u);   // RNE to bf16
    return (short)(u >> 16);
}

// ---------------- Kernel 1: cast x (f32 -> bf16), vectorized ----------------
__global__ __launch_bounds__(256) void cast_x_kernel(const float* __restrict__ x,
                                                     short* __restrict__ xb, long n) {
    long stride = (long)gridDim.x * blockDim.x * 8;
    for (long i = ((long)blockIdx.x * blockDim.x + threadIdx.x) * 8; i < n; i += stride) {
        float4 a = *(const float4*)(x + i);
        float4 b = *(const float4*)(x + i + 4);
        short8 o;
        o[0] = f2bf(a.x); o[1] = f2bf(a.y); o[2] = f2bf(a.z); o[3] = f2bf(a.w);
        o[4] = f2bf(b.x); o[5] = f2bf(b.y); o[6] = f2bf(b.z); o[7] = f2bf(b.w);
        *(short8*)(xb + i) = o;
    }
}

// ------ Kernel 2: cast centers (f32->bf16) + chalf[k] = 0.5*sum(c^2) in f32 ------
__global__ __launch_bounds__(256) void cast_centers_kernel(const float* __restrict__ c,
                                                           short* __restrict__ cb,
                                                           float* __restrict__ chalf, int dim) {
    int k = blockIdx.x;
    int t = threadIdx.x;
    const float* row = c + (size_t)k * dim;
    short* orow = cb + (size_t)k * dim;
    float s = 0.f;
    for (int i = t * 4; i < dim; i += blockDim.x * 4) {
        float4 v = *(const float4*)(row + i);
        s += v.x * v.x + v.y * v.y + v.z * v.z + v.w * v.w;
        short4 o;
        o.x = f2bf(v.x); o.y = f2bf(v.y); o.z = f2bf(v.z); o.w = f2bf(v.w);
        *(short4*)(orow + i) = o;
    }
#pragma unroll
    for (int off = 32; off; off >>= 1) s += __shfl_xor(s, off);
    __shared__ float red[4];
    if ((t & 63) == 0) red[t >> 6] = s;
    __syncthreads();
    if (t == 0) chalf[k] = 0.5f * (red[0] + red[1] + red[2] + red[3]);
}

// ------------- Kernel 3: 256x256 MFMA GEMM, K-half unit pipeline (T1+T2+T3+T4+T5) -------------
// logits[b,k] = cross[b,k] - 0.5*c_sq[k]   (row-constant -0.5*x_sq cancels in log_softmax)
//
// Staging unit = 32-wide K slice: A[256][32] (16 KB) + B[256][32] (16 KB) = 32 KB.
// Ring of 4 unit-buffers (128 KB LDS). While computing unit u, unit u+3's loads are
// issued (buffer (u+3)&3 was freed at unit u-1's final barrier). Steady-state
// s_waitcnt vmcnt(8) = 2 units in flight behind the one we're about to need.
//
// LDS layout per unit: LDS-row r (128 B) holds M-rows 2r,2r+1; 16B chunk of logical
// id L=(parity<<2)|kgrp stored at physical slot L ^ (r&7)  -> max 2-way bank aliasing
// (free). global_load_lds writes linearly, so the GLOBAL source address carries the
// inverse swizzle (both-sides-or-neither, rule #21).
#define BM 256
#define BN 256
#define UK 32

__global__ __launch_bounds__(512, 2) void gemm_logits_kernel(
    const short* __restrict__ xb,    // [M][K] bf16
    const short* __restrict__ cb,    // [N][K] bf16
    const float* __restrict__ chalf, // [N]
    float* __restrict__ out,         // [M][N]
    int M, int N, int K) {
    __shared__ char lds[131072];
    const int t = threadIdx.x;
    const int l = t & 63;
    const int w = t >> 6;
    const int wr = w >> 2, wc = w & 3;      // 2(M) x 4(N) wave grid; wave tile 128x64
    const int lr = l & 15, hi = l >> 4;

    // T1: XCD-aware swizzle (nwg = 256, divisible by 8)
    const int nnb = N / BN;                  // 4
    const int nwg = (M / BM) * nnb;          // 256
    const int bid = blockIdx.x;
    const int swz = (bid & 7) * (nwg >> 3) + (bid >> 3);
    const int brow = (swz / nnb) * BM;
    const int bcol = (swz % nnb) * BN;

    const size_t rowb = (size_t)K * 2;       // row stride, bytes

    // ---- staging precompute (512 thr x 16B = 8 KB = 64 LDS-rows per GLD round) ----
    const int sr = t >> 3;                   // LDS-row within round
    const int sl = t & 7;                    // physical slot
    const int Lg = sl ^ (sr & 7);            // logical chunk id (inverse swizzle)
    const int pb = Lg >> 2;                  // M-row parity
    const int ph = Lg & 3;                   // k-group (8 bf16)
    const char* gA = (const char*)xb + (size_t)(brow + 2 * sr + pb) * rowb + ph * 16;
    const char* gB = (const char*)cb + (size_t)(bcol + 2 * sr + pb) * rowb + ph * 16;
    const size_t rst = rowb * 128;           // +128 M-rows per round
    const int dst = t * 16;

#define GLD(gp, lo) __builtin_amdgcn_global_load_lds((const GLOBAL_AS int*)(gp), \
                        (LDS_AS int*)(lds + (lo)), 16, 0, 0)
#define STAGEA(uu) do { const size_t ko = (size_t)(uu) * (UK * 2);              \
        const int bb = ((uu) & 3) * 32768;                                      \
        GLD(gA + ko, bb + dst); GLD(gA + ko + rst, bb + 8192 + dst); } while (0)
#define STAGEB(uu) do { const size_t ko = (size_t)(uu) * (UK * 2);              \
        const int bb = ((uu) & 3) * 32768 + 16384;                              \
        GLD(gB + ko, bb + dst); GLD(gB + ko + rst, bb + 8192 + dst); } while (0)

    // ---- compute-side LDS offsets (constant per lane; frag m/n adds 1024 B) ----
    const int mrb = wr * 128 + lr;
    const int nrb = wc * 64 + lr;
    const int rA = mrb >> 1, rB = nrb >> 1;
    const int lA = ((lr & 1) << 2) | hi;     // logical chunk id for this lane
    const int aoff = rA * 128 + ((lA ^ (rA & 7)) << 4);
    const int boff = rB * 128 + ((lA ^ (rB & 7)) << 4) + 16384;

    f32x4 acc[8][4];
#pragma unroll
    for (int m = 0; m < 8; ++m)
#pragma unroll
        for (int n = 0; n < 4; ++n)
#pragma unroll
            for (int q = 0; q < 4; ++q) acc[m][n][q] = 0.f;

    const int nt = K / UK;                   // 32 units
    STAGEA(0); STAGEB(0);
    STAGEA(1); STAGEB(1);
    STAGEA(2); STAGEB(2);
    asm volatile("s_waitcnt vmcnt(8)" ::: "memory");   // unit 0 landed
    __builtin_amdgcn_s_barrier();

    for (int u = 0; u < nt; ++u) {
        const char* Ub = lds + (u & 3) * 32768;
        short8 af[4], af2[4], bf[4];
        // ---- phase 0: read af[0..3] + bf[0..3], issue A loads of u+3, 16 MFMA ----
#pragma unroll
        for (int m = 0; m < 4; ++m) af[m] = *(const short8*)(Ub + aoff + m * 1024);
#pragma unroll
        for (int n = 0; n < 4; ++n) bf[n] = *(const short8*)(Ub + boff + n * 1024);
        if (u + 3 < nt) STAGEA(u + 3);
        __builtin_amdgcn_sched_barrier(0);
        __builtin_amdgcn_s_barrier();
        __builtin_amdgcn_s_setprio(1);
#pragma unroll
        for (int m = 0; m < 4; ++m)
#pragma unroll
            for (int n = 0; n < 4; ++n)
                acc[m][n] = __builtin_amdgcn_mfma_f32_16x16x32_bf16(af[m], bf[n], acc[m][n], 0, 0, 0);
        __builtin_amdgcn_s_setprio(0);
        __builtin_amdgcn_sched_barrier(0);
        __builtin_amdgcn_s_barrier();
        // ---- phase 1: read af[4..7], issue B loads of u+3, 16 MFMA ----
#pragma unroll
        for (int m = 0; m < 4; ++m) af2[m] = *(const short8*)(Ub + aoff + (m + 4) * 1024);
        if (u + 3 < nt) STAGEB(u + 3);
        __builtin_amdgcn_sched_barrier(0);
        __builtin_amdgcn_s_barrier();
        __builtin_amdgcn_s_setprio(1);
#pragma unroll
        for (int m = 0; m < 4; ++m)
#pragma unroll
            for (int n = 0; n < 4; ++n)
                acc[m + 4][n] = __builtin_amdgcn_mfma_f32_16x16x32_bf16(af2[m], bf[n], acc[m + 4][n], 0, 0, 0);
        __builtin_amdgcn_s_setprio(0);
        // ---- unit boundary: ensure unit u+1 fully landed in ALL waves, then barrier ----
        const int rem = nt - 1 - u;
        if (rem >= 3)      { asm volatile("s_waitcnt vmcnt(8)" ::: "memory"); }
        else if (rem == 2) { asm volatile("s_waitcnt vmcnt(4)" ::: "memory"); }
        else if (rem == 1) { asm volatile("s_waitcnt vmcnt(0)" ::: "memory"); }
        __builtin_amdgcn_sched_barrier(0);
        __builtin_amdgcn_s_barrier();
    }

    // Epilogue: C/D frag layout col = lane&15, row = (lane>>4)*4 + reg
    float ch[4];
#pragma unroll
    for (int n = 0; n < 4; ++n) ch[n] = chalf[bcol + wc * 64 + n * 16 + lr];
#pragma unroll
    for (int m = 0; m < 8; ++m) {
        const int r0 = brow + wr * 128 + m * 16 + hi * 4;
#pragma unroll
        for (int n = 0; n < 4; ++n) {
            const int col = bcol + wc * 64 + n * 16 + lr;
#pragma unroll
            for (int q = 0; q < 4; ++q)
                out[(size_t)(r0 + q) * N + col] = acc[m][n][q] - ch[n];
        }
    }
#undef STAGEA
#undef STAGEB
#undef GLD
}

// ---------------- Kernel 4: in-place row log-softmax ----------------
__global__ __launch_bounds__(256) void logsoftmax_kernel(float* __restrict__ io, int N) {
    const int row = blockIdx.x;
    const int t = threadIdx.x;
    float* p = io + (size_t)row * N;
    float4 v = *(const float4*)(p + t * 4);
    float mx = fmaxf(fmaxf(v.x, v.y), fmaxf(v.z, v.w));
#pragma unroll
    for (int off = 32; off; off >>= 1) mx = fmaxf(mx, __shfl_xor(mx, off));
    __shared__ float sm[4], se[4];
    const int w = t >> 6, l = t & 63;
    if (l == 0) sm[w] = mx;
    __syncthreads();
    mx = fmaxf(fmaxf(sm[0], sm[1]), fmaxf(sm[2], sm[3]));
    float e = __expf(v.x - mx) + __expf(v.y - mx) + __expf(v.z - mx) + __expf(v.w - mx);
#pragma unroll
    for (int off = 32; off; off >>= 1) e += __shfl_xor(e, off);
    if (l == 0) se[w] = e;
    __syncthreads();
    const float lse = mx + __logf(se[0] + se[1] + se[2] + se[3]);
    float4 o;
    o.x = v.x - lse; o.y = v.y - lse; o.z = v.z - lse; o.w = v.w - lse;
    *(float4*)(p + t * 4) = o;
}

extern "C" void kernel_launch(void* const* d_in, const int* in_sizes, int n_in,
                              void* d_out, int out_size, void* d_ws, size_t ws_size,
                              hipStream_t stream) {
    const float* x = (const float*)d_in[0];
    const float* c = (const float*)d_in[1];
    float* out = (float*)d_out;

    int dim = (int)(sqrt((double)in_sizes[1]) + 0.5);   // 1024
    int batch = in_sizes[0] / dim;                      // 16384

    // workspace layout: [centers bf16][x bf16][chalf f32]
    size_t cb_bytes = (size_t)dim * dim * 2;
    size_t xb_bytes = (size_t)batch * dim * 2;
    short* cb = (short*)d_ws;
    short* xb = (short*)((char*)d_ws + cb_bytes);
    float* chalf = (float*)((char*)d_ws + cb_bytes + xb_bytes);

    cast_x_kernel<<<4096, 256, 0, stream>>>(x, xb, (long)batch * dim);
    cast_centers_kernel<<<dim, 256, 0, stream>>>(c, cb, chalf, dim);

    int nblocks = (batch / BM) * (dim / BN);            // 256
    gemm_logits_kernel<<<nblocks, 512, 0, stream>>>(xb, cb, chalf, out, batch, dim, dim);

    logsoftmax_kernel<<<batch, 256, 0, stream>>>(out, dim);
}

// Round 4
// 73.179 us; speedup vs baseline: 1.1566x; 1.1566x over previous
//
#include <hip/hip_runtime.h>
#include <math.h>

typedef __attribute__((ext_vector_type(8))) short short8;
typedef __attribute__((ext_vector_type(4))) float f32x4;

#define GLOBAL_AS __attribute__((address_space(1)))
#define LDS_AS __attribute__((address_space(3)))

__device__ inline short f2bf(float f) {
    unsigned u = __float_as_uint(f);
    u += 0x7FFFu + ((u >> 16) & 1u);   // RNE to bf16
    return (short)(u >> 16);
}

// ------ Kernel 1: cast centers (f32->bf16) + chalf[k] = 0.5*sum(c^2) in f32 ------
__global__ __launch_bounds__(256) void cast_centers_kernel(const float* __restrict__ c,
                                                           short* __restrict__ cb,
                                                           float* __restrict__ chalf, int dim) {
    int k = blockIdx.x;
    int t = threadIdx.x;
    const float* row = c + (size_t)k * dim;
    short* orow = cb + (size_t)k * dim;
    float s = 0.f;
    for (int i = t * 4; i < dim; i += blockDim.x * 4) {
        float4 v = *(const float4*)(row + i);
        s += v.x * v.x + v.y * v.y + v.z * v.z + v.w * v.w;
        short4 o;
        o.x = f2bf(v.x); o.y = f2bf(v.y); o.z = f2bf(v.z); o.w = f2bf(v.w);
        *(short4*)(orow + i) = o;
    }
#pragma unroll
    for (int off = 32; off; off >>= 1) s += __shfl_xor(s, off);
    __shared__ float red[4];
    if ((t & 63) == 0) red[t >> 6] = s;
    __syncthreads();
    if (t == 0) chalf[k] = 0.5f * (red[0] + red[1] + red[2] + red[3]);
}

// ------------- Kernel 2: fused GEMM (64 x FULL-ROW 1024) + log-softmax epilogue -------------
// logits[b,k] = x_b . c_k - 0.5*||c_k||^2  (row-constant -0.5*||x||^2 cancels in log_softmax)
// out[b,k] = logits[b,k] - logsumexp_k(logits[b,:])
//
// BM=64 rows/block, BN=N=1024 (full rows -> softmax fused). 8 waves, wave tile 64x128.
// UK=32 K-slice units, ring-2 LDS (A bf16 4KB + B bf16 64KB per slot = 136KB total).
// A: reg-staged f32 -> cvt bf16 -> ds_write (read once from HBM, no cast kernel).
// B: global_load_lds, XOR-swizzled both-sides (linear dest, inverse-swizzled source).
// LDS rows are 64B (32 bf16); 16B slot s of row r stored at s ^ ((r>>1)&3) -> 2-way max (free).
#define BM 64
#define UK 32
#define SLOT 69632   // 4KB A + 64KB B

__global__ __launch_bounds__(512, 2) void fused_kernel(
    const float* __restrict__ x,     // [M][K] f32
    const short* __restrict__ cb,    // [N][K] bf16
    const float* __restrict__ chalf, // [N]
    float* __restrict__ out,         // [M][N]
    int M, int N, int K) {
    __shared__ char lds[2 * SLOT];
    const int t = threadIdx.x;
    const int l = t & 63, w = t >> 6, lr = l & 15, hi = l >> 4;
    const int brow = blockIdx.x * BM;

    // ---- fragment-read offsets (swizzle term identical for A and B reads) ----
    const int sw = (hi ^ ((lr >> 1) & 3)) << 4;
    const int aoff = lr * 64 + sw;                       // + m*1024, + slot base
    const int boff = 4096 + (w * 128 + lr) * 64 + sw;    // + n*1024, + slot base

    // ---- A reg-stage addressing: thread t covers row t>>3, f32 cols (t&7)*4.. ----
    const int ar = t >> 3, ac = t & 7;
    const float* xsrc = x + (size_t)(brow + ar) * K + ac * 4;
    const int awaddr = ar * 64 + (((ac >> 1) ^ ((ar >> 1) & 3)) << 4) + (ac & 1) * 8;

    // ---- B global_load_lds addressing (inverse-swizzled source, linear dest) ----
    const int lgb = (t & 3) ^ ((t >> 3) & 3);
    const char* bsrc = (const char*)cb + (size_t)(t >> 2) * (K * 2) + lgb * 16;
    const size_t bjs = (size_t)128 * K * 2;              // +128 rows per round

#define GLD(gp, lo) __builtin_amdgcn_global_load_lds((const GLOBAL_AS int*)(gp), \
                        (LDS_AS int*)(lds + (lo)), 16, 0, 0)
#define STAGEB(sl, uu) do {                                                     \
    _Pragma("unroll")                                                           \
    for (int j = 0; j < 8; ++j)                                                 \
        GLD(bsrc + (size_t)j * bjs + (size_t)(uu) * 64, (sl)*SLOT + 4096 + j*8192 + t*16); \
    } while (0)
#define AWRITE(sl, fv) do {                                                     \
    short4 v_; v_.x = f2bf((fv).x); v_.y = f2bf((fv).y);                        \
    v_.z = f2bf((fv).z); v_.w = f2bf((fv).w);                                   \
    *(short4*)(lds + (sl)*SLOT + awaddr) = v_; } while (0)

    f32x4 acc[4][8];
#pragma unroll
    for (int m = 0; m < 4; ++m)
#pragma unroll
        for (int n = 0; n < 8; ++n)
#pragma unroll
            for (int q = 0; q < 4; ++q) acc[m][n][q] = 0.f;

    const int nt = K / UK;                   // 32
    // ---- prologue: stage unit 0 into slot 0 ----
    {
        float4 fa = *(const float4*)(xsrc);
        STAGEB(0, 0);
        AWRITE(0, fa);
        asm volatile("s_waitcnt vmcnt(0) lgkmcnt(0)" ::: "memory");
    }
    __builtin_amdgcn_s_barrier();

    for (int u = 0; u < nt; ++u) {
        const char* Ab = lds + (u & 1) * SLOT;
        const int nx = u + 1;
        const int nsl = nx & 1;
        short8 af[4], bfr[8];
        float4 fa;
        // ---- phase 0: A+B(0..3) frag reads, issue ALL next-unit staging, MFMA n0..3 ----
        if (nx < nt) fa = *(const float4*)(xsrc + (size_t)nx * UK);
#pragma unroll
        for (int m = 0; m < 4; ++m) af[m] = *(const short8*)(Ab + aoff + m * 1024);
#pragma unroll
        for (int n = 0; n < 4; ++n) bfr[n] = *(const short8*)(Ab + boff + n * 1024);
        if (nx < nt) STAGEB(nsl, nx);
        __builtin_amdgcn_sched_barrier(0);
        __builtin_amdgcn_s_barrier();
        __builtin_amdgcn_s_setprio(1);
#pragma unroll
        for (int m = 0; m < 4; ++m)
#pragma unroll
            for (int n = 0; n < 4; ++n)
                acc[m][n] = __builtin_amdgcn_mfma_f32_16x16x32_bf16(af[m], bfr[n], acc[m][n], 0, 0, 0);
        __builtin_amdgcn_s_setprio(0);
        __builtin_amdgcn_sched_barrier(0);
        __builtin_amdgcn_s_barrier();
        // ---- phase 1: B(4..7) frag reads, A cvt+ds_write for next unit, MFMA n4..7 ----
#pragma unroll
        for (int n = 4; n < 8; ++n) bfr[n] = *(const short8*)(Ab + boff + n * 1024);
        if (nx < nt) AWRITE(nsl, fa);
        __builtin_amdgcn_sched_barrier(0);
        __builtin_amdgcn_s_setprio(1);
#pragma unroll
        for (int m = 0; m < 4; ++m)
#pragma unroll
            for (int n = 4; n < 8; ++n)
                acc[m][n] = __builtin_amdgcn_mfma_f32_16x16x32_bf16(af[m], bfr[n], acc[m][n], 0, 0, 0);
        __builtin_amdgcn_s_setprio(0);
        asm volatile("s_waitcnt vmcnt(0) lgkmcnt(0)" ::: "memory");
        __builtin_amdgcn_sched_barrier(0);
        __builtin_amdgcn_s_barrier();
    }

    // ================= fused log-softmax epilogue =================
    // C/D frag layout: col = lane&15 (-> center index via n,lr), row = (lane>>4)*4 + q.
    // Lane holds rows R = m*16 + hi*4 + q (16 of them), cols w*128 + n*16 + lr (8 each).
    float ch[8];
#pragma unroll
    for (int n = 0; n < 8; ++n) ch[n] = chalf[w * 128 + n * 16 + lr];

    // pass 1: per-lane max over n, reduce over lr-lanes, cross-wave via LDS
    float pm[4][4];
#pragma unroll
    for (int m = 0; m < 4; ++m)
#pragma unroll
        for (int q = 0; q < 4; ++q) {
            float v = acc[m][0][q] - ch[0];
#pragma unroll
            for (int n = 1; n < 8; ++n) v = fmaxf(v, acc[m][n][q] - ch[n]);
            pm[m][q] = v;
        }
#pragma unroll
    for (int d = 1; d <= 8; d <<= 1)
#pragma unroll
        for (int m = 0; m < 4; ++m)
#pragma unroll
            for (int q = 0; q < 4; ++q) pm[m][q] = fmaxf(pm[m][q], __shfl_xor(pm[m][q], d));
    if (lr == 0) {
#pragma unroll
        for (int m = 0; m < 4; ++m)
#pragma unroll
            for (int q = 0; q < 4; ++q)
                *(float*)(lds + (m * 16 + hi * 4 + q) * 32 + w * 4) = pm[m][q];   // wmax[R][w]
    }
    __syncthreads();
    if (t < 64) {
        float4 a = *(const float4*)(lds + t * 32);
        float4 b = *(const float4*)(lds + t * 32 + 16);
        float g = fmaxf(fmaxf(fmaxf(a.x, a.y), fmaxf(a.z, a.w)),
                        fmaxf(fmaxf(b.x, b.y), fmaxf(b.z, b.w)));
        *(float*)(lds + 4096 + t * 4) = g;                                        // gmax[R]
    }
    __syncthreads();

    // pass 2: sum of exp
    float ps[4][4];
#pragma unroll
    for (int m = 0; m < 4; ++m)
#pragma unroll
        for (int q = 0; q < 4; ++q) {
            const float g = *(const float*)(lds + 4096 + (m * 16 + hi * 4 + q) * 4);
            float s = 0.f;
#pragma unroll
            for (int n = 0; n < 8; ++n) s += __expf(acc[m][n][q] - ch[n] - g);
            ps[m][q] = s;
        }
#pragma unroll
    for (int d = 1; d <= 8; d <<= 1)
#pragma unroll
        for (int m = 0; m < 4; ++m)
#pragma unroll
            for (int q = 0; q < 4; ++q) ps[m][q] += __shfl_xor(ps[m][q], d);
    if (lr == 0) {
#pragma unroll
        for (int m = 0; m < 4; ++m)
#pragma unroll
            for (int q = 0; q < 4; ++q)
                *(float*)(lds + 2048 + (m * 16 + hi * 4 + q) * 32 + w * 4) = ps[m][q]; // wsum[R][w]
    }
    __syncthreads();
    if (t < 64) {
        float4 a = *(const float4*)(lds + 2048 + t * 32);
        float4 b = *(const float4*)(lds + 2048 + t * 32 + 16);
        float s = (a.x + a.y + a.z + a.w) + (b.x + b.y + b.z + b.w);
        *(float*)(lds + 4352 + t * 4) = *(const float*)(lds + 4096 + t * 4) + __logf(s); // lse[R]
    }
    __syncthreads();

    // write final output
#pragma unroll
    for (int m = 0; m < 4; ++m)
#pragma unroll
        for (int q = 0; q < 4; ++q) {
            const int R = m * 16 + hi * 4 + q;
            const float lse = *(const float*)(lds + 4352 + R * 4);
            float* orow = out + (size_t)(brow + R) * N + w * 128 + lr;
#pragma unroll
            for (int n = 0; n < 8; ++n)
                orow[n * 16] = acc[m][n][q] - ch[n] - lse;
        }
#undef STAGEB
#undef AWRITE
#undef GLD
}

extern "C" void kernel_launch(void* const* d_in, const int* in_sizes, int n_in,
                              void* d_out, int out_size, void* d_ws, size_t ws_size,
                              hipStream_t stream) {
    const float* x = (const float*)d_in[0];
    const float* c = (const float*)d_in[1];
    float* out = (float*)d_out;

    int dim = (int)(sqrt((double)in_sizes[1]) + 0.5);   // 1024
    int batch = in_sizes[0] / dim;                      // 16384

    // workspace layout: [centers bf16][chalf f32]
    size_t cb_bytes = (size_t)dim * dim * 2;
    short* cb = (short*)d_ws;
    float* chalf = (float*)((char*)d_ws + cb_bytes);

    cast_centers_kernel<<<dim, 256, 0, stream>>>(c, cb, chalf, dim);

    fused_kernel<<<batch / BM, 512, 0, stream>>>(x, cb, chalf, out, batch, dim, dim);
}